// Round 1
// baseline (823.541 us; speedup 1.0000x reference)
//
#include <hip/hip_runtime.h>

// RNNPool fused kernel for MI355X (gfx950).
// B=16384, D=64, R=C=8, H=Hb=64.
// One block = 8 batch elements, 256 threads (4 waves), ~94KB LDS.
// All matmuls via v_mfma_f32_16x16x32_f16 (f32 accumulate), elementwise in f32.

typedef _Float16 f16;
typedef _Float16 f16x8 __attribute__((ext_vector_type(8)));
typedef float f32x4 __attribute__((ext_vector_type(4)));

#define DEV static __device__ __forceinline__

DEV float fsigmoid(float x) { return 1.0f / (1.0f + __expf(-x)); }
DEV float ftanh(float x) { return 1.0f - 2.0f / (__expf(2.0f * x) + 1.0f); }

// Load a B-operand fragment for mfma_16x16x32 from a row-major [64(k)][64(n)] f32
// weight matrix. Fragment = Y[n][k] with Y = W^T: lane holds n = nt*16+(lane&15),
// k = kq*32 + 8*(lane>>4) + j  (j=0..7).
DEV f16x8 load_wfrag(const float* __restrict__ Wg, int nt, int kq, int lane) {
    f16x8 r;
    int n = nt * 16 + (lane & 15);
    int k0 = kq * 32 + ((lane >> 4) << 3);
#pragma unroll
    for (int j = 0; j < 8; ++j) r[j] = (f16)Wg[(k0 + j) * 64 + n];
    return r;
}

__global__ void __launch_bounds__(256, 1)
rnnpool_kernel(const float* __restrict__ x,
               const float* __restrict__ W1, const float* __restrict__ U1,
               const float* __restrict__ bg1, const float* __restrict__ bu1,
               const float* __restrict__ zeta1, const float* __restrict__ nu1,
               const float* __restrict__ W2, const float* __restrict__ U2,
               const float* __restrict__ bg2, const float* __restrict__ bu2,
               const float* __restrict__ zeta2, const float* __restrict__ nu2,
               const float* __restrict__ h0_row, const float* __restrict__ h0_col,
               const float* __restrict__ h0_bd_row, const float* __restrict__ h0_bd_col,
               float* __restrict__ out, int Bt)
{
    // LDS layout (f16 elements):
    //   wxl : [8 b][8 kb][64 rc][8]      = 32768   (Wx for both passes, k-major)
    //   hb  : [2 buf][8 kb][64 row][8]   = 8192    (recurrence h, double buffered)
    //   stl : [8 kb][64 row][8]          = 4096    (final states of a pass)
    //   h2b : [2 buf][8 kb][16 row][8]   = 2048    (bidir hidden)
    extern __shared__ f16 lds[];
    f16* wxl = lds;
    f16* hb  = lds + 32768;
    f16* stl = lds + 32768 + 8192;
    f16* h2b = lds + 32768 + 8192 + 4096;

    const int tid  = threadIdx.x;
    const int lane = tid & 63;
    const int w    = tid >> 6;       // wave 0..3
    const int blk  = blockIdx.x;
    const int l15  = lane & 15;
    const int lg   = lane >> 4;      // lane group 0..3

    const float zt1  = fsigmoid(zeta1[0]);
    const float ntc1 = fsigmoid(nu1[0]);
    const float zt2  = fsigmoid(zeta2[0]);
    const float ntc2 = fsigmoid(nu2[0]);

    // ---------------- Phase 0: Wx[b][rc][j] = sum_d x[b,d,rc] * W1[d,j] ----------------
    {
        f16x8 wf[4][2];
#pragma unroll
        for (int nt = 0; nt < 4; ++nt)
#pragma unroll
            for (int kq = 0; kq < 2; ++kq)
                wf[nt][kq] = load_wfrag(W1, nt, kq, lane);

#pragma unroll 2
        for (int s = 0; s < 8; ++s) {
            int T = w * 8 + s;           // 32 M-tiles total: (b, tt)
            int b = T >> 2, tt = T & 3;
            const float* xb = x + ((size_t)((blk << 3) + b)) * 4096;
            int rc = tt * 16 + l15;      // A-frag row
            f16x8 af[2];
#pragma unroll
            for (int kq = 0; kq < 2; ++kq) {
#pragma unroll
                for (int j = 0; j < 8; ++j) {
                    int d = kq * 32 + (lg << 3) + j;
                    af[kq][j] = (f16)xb[d * 64 + rc];
                }
            }
            f32x4 acc[4];
#pragma unroll
            for (int nt = 0; nt < 4; ++nt) acc[nt] = (f32x4){0.f, 0.f, 0.f, 0.f};
#pragma unroll
            for (int nt = 0; nt < 4; ++nt)
#pragma unroll
                for (int kq = 0; kq < 2; ++kq)
                    acc[nt] = __builtin_amdgcn_mfma_f32_16x16x32_f16(af[kq], wf[nt][kq], acc[nt], 0, 0, 0);
            // D layout: row = tt*16 + 4*lg + i, col j = nt*16 + l15
#pragma unroll
            for (int nt = 0; nt < 4; ++nt) {
                int j = nt * 16 + l15;
#pragma unroll
                for (int i = 0; i < 4; ++i) {
                    int row = tt * 16 + (lg << 2) + i;
                    wxl[(((b << 3) + (j >> 3)) << 9) + (row << 3) + (j & 7)] = (f16)acc[nt][i];
                }
            }
        }
    }

    // ---------------- Two passes: 0 = rows (time = r), 1 = cols (time = c) ----------------
#pragma unroll 1
    for (int pass = 0; pass < 2; ++pass) {
        const float* h0g  = pass ? h0_col    : h0_row;
        const float* h0bd = pass ? h0_bd_col : h0_bd_row;
        const int outoff  = pass ? 128 : 0;

        // ---- init recurrence h: LDS buf0 (f16, k-major) + f32 regs (D-layout) ----
#pragma unroll
        for (int it = 0; it < 2; ++it) {
            int idx = tid + (it << 8);      // 0..511 -> (rho, jb)
            int rho = idx >> 3, jb = idx & 7;
            int t = rho >> 3, b = rho & 7;  // rho = t*8 + b  (t = c for rows, r for cols)
            const float* src = h0g + ((size_t)(t * Bt + (blk << 3) + b)) * 64 + (jb << 3);
            f16x8 v;
#pragma unroll
            for (int j = 0; j < 8; ++j) v[j] = (f16)src[j];
            *(f16x8*)&hb[(jb << 9) + (rho << 3)] = v;   // buf 0
        }
        float hreg[4][4];
#pragma unroll
        for (int nt = 0; nt < 4; ++nt)
#pragma unroll
            for (int i = 0; i < 4; ++i) {
                int rho = (w << 4) + (lg << 2) + i;
                int t = rho >> 3, b = rho & 7;
                hreg[nt][i] = h0g[((size_t)(t * Bt + (blk << 3) + b)) * 64 + nt * 16 + l15];
            }
        float bgv[4], buv[4];
#pragma unroll
        for (int nt = 0; nt < 4; ++nt) {
            bgv[nt] = bg1[nt * 16 + l15];
            buv[nt] = bu1[nt * 16 + l15];
        }
        f16x8 uf[4][2];
#pragma unroll
        for (int nt = 0; nt < 4; ++nt)
#pragma unroll
            for (int kq = 0; kq < 2; ++kq)
                uf[nt][kq] = load_wfrag(U1, nt, kq, lane);

        __syncthreads();

        // ---- main recurrence: 8 steps, rows rho = (t-index)*8 + b ----
#pragma unroll 1
        for (int t = 0; t < 8; ++t) {
            int cur = t & 1, nxt = cur ^ 1;
            f16x8 hf[2];
#pragma unroll
            for (int kq = 0; kq < 2; ++kq)
                hf[kq] = *(const f16x8*)&hb[(((cur << 3) + (kq << 2) + lg) << 9) + (((w << 4) + l15) << 3)];
            f32x4 acc[4];
#pragma unroll
            for (int nt = 0; nt < 4; ++nt) acc[nt] = (f32x4){0.f, 0.f, 0.f, 0.f};
#pragma unroll
            for (int nt = 0; nt < 4; ++nt)
#pragma unroll
                for (int kq = 0; kq < 2; ++kq)
                    acc[nt] = __builtin_amdgcn_mfma_f32_16x16x32_f16(hf[kq], uf[nt][kq], acc[nt], 0, 0, 0);
#pragma unroll
            for (int nt = 0; nt < 4; ++nt) {
                int j = nt * 16 + l15;
#pragma unroll
                for (int i = 0; i < 4; ++i) {
                    int rho = (w << 4) + (lg << 2) + i;
                    // rows pass: rho = c*8+b, rc = t*8 + c ; cols pass: rho = r*8+b, rc = r*8 + t
                    int rc = (pass == 0) ? ((t << 3) + (rho >> 3)) : (((rho >> 3) << 3) + t);
                    int b = rho & 7;
                    float wxv = (float)wxl[(((b << 3) + (j >> 3)) << 9) + (rc << 3) + (j & 7)];
                    float pre = acc[nt][i] + wxv;
                    float z  = fsigmoid(pre + bgv[nt]);
                    float cc = ftanh(pre + buv[nt]);
                    float hn = z * hreg[nt][i] + (zt1 * (1.0f - z) + ntc1) * cc;
                    hreg[nt][i] = hn;
                    f16 h16 = (f16)hn;
                    hb[(((nxt << 3) + (j >> 3)) << 9) + (rho << 3) + (j & 7)] = h16;
                    if (t == 7) stl[((j >> 3) << 9) + (rho << 3) + (j & 7)] = h16;
                }
            }
            __syncthreads();
        }

        // ---- bidirectional pass over states (T=8), fwd+bwd packed as M=16 tile ----
        f16x8 w2f[2], u2f[2];
#pragma unroll
        for (int kq = 0; kq < 2; ++kq) {
            w2f[kq] = load_wfrag(W2, w, kq, lane);
            u2f[kq] = load_wfrag(U2, w, kq, lane);
        }
        const int j2 = (w << 4) + l15;   // this wave's output column
        float h2r[4];
#pragma unroll
        for (int i = 0; i < 4; ++i) {
            int row = (lg << 2) + i;     // row = dir*8 + b
            int dir = row >> 3, b = row & 7;
            h2r[i] = h0bd[((size_t)(dir * Bt + (blk << 3) + b)) * 64 + j2];
        }
        if (tid < 128) {
            int row = tid >> 3, jb = tid & 7;
            int dir = row >> 3, b = row & 7;
            const float* src = h0bd + ((size_t)(dir * Bt + (blk << 3) + b)) * 64 + (jb << 3);
            f16x8 v;
#pragma unroll
            for (int j = 0; j < 8; ++j) v[j] = (f16)src[j];
            *(f16x8*)&h2b[(jb << 7) + (row << 3)] = v;   // buf 0
        }
        const float bgs = bg2[j2], bus = bu2[j2];
        __syncthreads();

#pragma unroll 1
        for (int t = 0; t < 8; ++t) {
            int cur = t & 1, nxt = cur ^ 1;
            // A-frag rows: row16 = lane&15 = dir*8 + b; fwd uses states[t], bwd states[7-t]
            int dirA = l15 >> 3, bbA = l15 & 7;
            int tuse = dirA ? (7 - t) : t;
            int srow = (tuse << 3) + bbA;
            f16x8 sf[2], h2f[2];
#pragma unroll
            for (int kq = 0; kq < 2; ++kq) {
                sf[kq]  = *(const f16x8*)&stl[(((kq << 2) + lg) << 9) + (srow << 3)];
                h2f[kq] = *(const f16x8*)&h2b[(((cur << 3) + (kq << 2) + lg) << 7) + (l15 << 3)];
            }
            f32x4 acc = (f32x4){0.f, 0.f, 0.f, 0.f};
#pragma unroll
            for (int kq = 0; kq < 2; ++kq)
                acc = __builtin_amdgcn_mfma_f32_16x16x32_f16(sf[kq], w2f[kq], acc, 0, 0, 0);
#pragma unroll
            for (int kq = 0; kq < 2; ++kq)
                acc = __builtin_amdgcn_mfma_f32_16x16x32_f16(h2f[kq], u2f[kq], acc, 0, 0, 0);
#pragma unroll
            for (int i = 0; i < 4; ++i) {
                int row = (lg << 2) + i;
                float pre = acc[i];            // = states.W2 + h2.U2
                float z  = fsigmoid(pre + bgs);
                float cc = ftanh(pre + bus);
                h2r[i] = z * h2r[i] + (zt2 * (1.0f - z) + ntc2) * cc;
                h2b[(((nxt << 3) + (j2 >> 3)) << 7) + (row << 3) + (j2 & 7)] = (f16)h2r[i];
            }
            __syncthreads();
        }

        // ---- write outputs: out[b][outoff + dir*64 + j2] ----
#pragma unroll
        for (int i = 0; i < 4; ++i) {
            int row = (lg << 2) + i;
            int dir = row >> 3, b = row & 7;
            out[((size_t)((blk << 3) + b)) * 256 + outoff + (dir << 6) + j2] = h2r[i];
        }
        __syncthreads();
    }
}

extern "C" void kernel_launch(void* const* d_in, const int* in_sizes, int n_in,
                              void* d_out, int out_size, void* d_ws, size_t ws_size,
                              hipStream_t stream)
{
    const float* x     = (const float*)d_in[0];
    // d_in[1] = batch_size (int scalar) — unused
    const float* W1    = (const float*)d_in[2];
    const float* U1    = (const float*)d_in[3];
    const float* bg1   = (const float*)d_in[4];
    const float* bu1   = (const float*)d_in[5];
    const float* zeta1 = (const float*)d_in[6];
    const float* nu1   = (const float*)d_in[7];
    const float* W2    = (const float*)d_in[8];
    const float* U2    = (const float*)d_in[9];
    const float* bg2   = (const float*)d_in[10];
    const float* bu2   = (const float*)d_in[11];
    const float* zeta2 = (const float*)d_in[12];
    const float* nu2   = (const float*)d_in[13];
    const float* h0r   = (const float*)d_in[14];
    const float* h0c   = (const float*)d_in[15];
    const float* h0br  = (const float*)d_in[16];
    const float* h0bc  = (const float*)d_in[17];
    float* outp = (float*)d_out;

    int Bt = in_sizes[0] / 4096;     // B = 16384 (D*R*C = 4096)
    int grid = Bt >> 3;              // 8 batch elements per block
    size_t shmem = (size_t)(32768 + 8192 + 4096 + 2048) * sizeof(f16);  // 94208 B

    hipFuncSetAttribute((const void*)rnnpool_kernel,
                        hipFuncAttributeMaxDynamicSharedMemorySize, (int)shmem);
    rnnpool_kernel<<<grid, 256, shmem, stream>>>(
        x, W1, U1, bg1, bu1, zeta1, nu1,
        W2, U2, bg2, bu2, zeta2, nu2,
        h0r, h0c, h0br, h0bc, outp, Bt);
}